// Round 6
// baseline (369.770 us; speedup 1.0000x reference)
//
#include <hip/hip_runtime.h>
#include <math.h>

// Problem constants (N = 1024)
#define M_ROWS  81920            // 1024*8*10 score rows
#define NCOLS   4096
#define KPAD    48               // 45 padded to 48 (3 k-tiles of 16 for 32x32x16)
#define NCHUNK  4
#define CHUNKC  (NCOLS / NCHUNK) // 1024 cols per chunk
#define CROUNDS (CHUNKC / 32)    // 32 col-rounds of 32 cols per chunk
#define GROUNDS (NCOLS / 32)     // 128 global rounds
#define FRAG    512              // halves per fragment block (64 lanes x 8)
#define ROUNDH  (3 * FRAG)       // halves per round per matrix (3 k-tiles)
#define LO_SCALE 4096.0f         // 2^12: keeps f16 residuals out of subnormal range
#define INV_LO   (1.0f / 4096.0f)

typedef _Float16 f16x8  __attribute__((ext_vector_type(8)));
typedef float    f32x16 __attribute__((ext_vector_type(16)));

// ws layout (~3.4 MB). ORDER MATTERS: the pipelined GEMM's final prefetch
// overreads one round (3 KB) past Bhi_pk (lands in Blo_pk) and past Blo_pk
// (lands in pbest) — values unused, memory must be valid.
//   Bhi_pk: _Float16[128 * 1536]  (MFMA-fragment order)   384 KB
//   Blo_pk: _Float16[128 * 1536]  (residual * 2^12)       384 KB
//   pbest : float[81920 * 4]                              1.31 MB
//   pidx  : int  [81920 * 4]                              1.31 MB

// ---------------------------------------------------------------------------
// Build B in MFMA-fragment order. For round r (cols 32r..32r+31), k-tile kt,
// the 1 KB block at (r*3+kt)*FRAG holds lane l's 8 halves at l*8:
//   lane l = half*32 + l31  ->  B[k = kt*16 + half*8 + j][col = 32r + l31].
// One thread per column n: writes two f16x8 groups per kt (half 0 and 1),
// coalesced across the 32 threads of a round.
__global__ void build_B_kernel(const float* __restrict__ H,
                               _Float16* __restrict__ Bhi_pk,
                               _Float16* __restrict__ Blo_pk) {
    const int n = blockIdx.x * 256 + threadIdx.x;
    const int r = n >> 5;
    const int l = n & 31;
    float hi[KPAD], lo[KPAD];
    #pragma unroll
    for (int k = 0; k < 45; ++k) {
        const float h = H[k * NCOLS + n];
        const _Float16 h1 = (_Float16)h;
        hi[k] = (float)h1;
        lo[k] = (h - (float)h1) * LO_SCALE;
    }
    #pragma unroll
    for (int k = 45; k < KPAD; ++k) { hi[k] = 0.f; lo[k] = 0.f; }
    #pragma unroll
    for (int kt = 0; kt < 3; ++kt) {
        f16x8 h0, h1v, l0, l1v;
        #pragma unroll
        for (int j = 0; j < 8; ++j) {
            h0[j]  = (_Float16)hi[kt * 16 + j];
            h1v[j] = (_Float16)hi[kt * 16 + 8 + j];
            l0[j]  = (_Float16)lo[kt * 16 + j];
            l1v[j] = (_Float16)lo[kt * 16 + 8 + j];
        }
        _Float16* dh = Bhi_pk + (size_t)(r * 3 + kt) * FRAG;
        _Float16* dl = Blo_pk + (size_t)(r * 3 + kt) * FRAG;
        *(f16x8*)(dh + l * 8)        = h0;    // half 0 lane
        *(f16x8*)(dh + (l + 32) * 8) = h1v;   // half 1 lane
        *(f16x8*)(dl + l * 8)        = l0;
        *(f16x8*)(dl + (l + 32) * 8) = l1v;
    }
}

// ---------------------------------------------------------------------------
// MFMA GEMM + fused argmax, 32x32x16 shape, inline A, packed coalesced B.
// wave = 64 rows (2 row-tiles of 32) x 1024-col chunk, 32-col rounds,
// branch-free double-buffered B prefetch (loads are base + lane*16 + imm:
// one 1 KB fully-coalesced transaction each).
// 32x32 layouts (m74/m101-verified): A[m=lane&31][k=(lane>>5)*8+j];
// B[k=(lane>>5)*8+j][n=lane&31]; C/D col=lane&31, row=(e&3)+8*(e>>2)+4*(lane>>5).
__global__ __launch_bounds__(256, 4) void score_argmax_kernel(
        const float* __restrict__ x,   // (1024, 480)
        const float* __restrict__ S,   // (30, 2, 15)
        const float* __restrict__ T,   // (30, 15)
        const _Float16* __restrict__ Bhi_pk,
        const _Float16* __restrict__ Blo_pk,
        float* __restrict__ pbest,
        int*   __restrict__ pidx) {
    const int tid  = threadIdx.x;
    const int lane = tid & 63;
    const int l31  = lane & 31;
    const int half = lane >> 5;                       // 0 or 1
    const int chunk = blockIdx.x / 320;               // block-uniform
    const int rg    = (blockIdx.x - chunk * 320) * 4 + (tid >> 6);  // [0,1280)
    const int rowbase = rg * 64;

    // ---- inline A: afr[rt][kt][j] = y(rowbase + rt*32 + l31, kt*16 + half*8 + j)
    // y = sign(x4·S - T - 1e-4), exactly ±1/0 in f16; zero for k >= 45.
    f16x8 afr[2][3];
    #pragma unroll
    for (int rt = 0; rt < 2; ++rt) {
        const int row  = rowbase + rt * 32 + l31;
        const int pair = row / 10;
        const int c2   = row - pair * 10;
        const int a    = pair >> 3;
        const int b    = pair & 7;
        const float* xp = x + a * 480 + b * 60;
        #pragma unroll
        for (int kt = 0; kt < 3; ++kt) {
            #pragma unroll
            for (int j = 0; j < 8; ++j) {
                const int k    = kt * 16 + half * 8 + j;     // [0,48)
                const bool pad = (k >= 45);
                const int kcl  = pad ? 0 : k;                // clamp for safe addrs
                const int cc   = kcl / 15;
                const int kk   = kcl - cc * 15;
                const int c    = c2 * 3 + cc;
                const float x0 = xp[c * 2 + 0];
                const float x1 = xp[c * 2 + 1];
                float v = x0 * S[(c * 2 + 0) * 15 + kk] + x1 * S[(c * 2 + 1) * 15 + kk];
                v = v - T[c * 15 + kk] - 1e-4f;
                const float yv = (v > 0.f) ? 1.f : ((v < 0.f) ? -1.f : 0.f);
                afr[rt][kt][j] = pad ? (_Float16)0.f : (_Float16)yv;
            }
        }
    }

    float best[2][16];
    int   bidx[2][16];
    #pragma unroll
    for (int rt = 0; rt < 2; ++rt)
        #pragma unroll
        for (int e = 0; e < 16; ++e) { best[rt][e] = -INFINITY; bidx[rt][e] = 0; }

    const int colbase0 = chunk * CHUNKC;
    // per-lane packed base for this chunk's first round
    const _Float16* hbase = Bhi_pk + (size_t)(chunk * CROUNDS) * ROUNDH + lane * 8;
    const _Float16* lbase = Blo_pk + (size_t)(chunk * CROUNDS) * ROUNDH + lane * 8;

    // double-buffered B fragments (hi/lo x 3 k-tiles); all loads unconditional.
    f16x8 cb[6], nb[6];
    #pragma unroll
    for (int kt = 0; kt < 3; ++kt) {
        cb[kt]     = *(const f16x8*)(hbase + kt * FRAG);
        cb[3 + kt] = *(const f16x8*)(lbase + kt * FRAG);
    }

    for (int ct = 0; ct < CROUNDS; ++ct) {
        // prefetch round ct+1 (final iter overreads 3KB into adjacent ws: valid)
        {
            const _Float16* hp = hbase + (size_t)(ct + 1) * ROUNDH;
            const _Float16* lp = lbase + (size_t)(ct + 1) * ROUNDH;
            #pragma unroll
            for (int kt = 0; kt < 3; ++kt) {
                nb[kt]     = *(const f16x8*)(hp + kt * FRAG);
                nb[3 + kt] = *(const f16x8*)(lp + kt * FRAG);
            }
        }
        const int mycol = colbase0 + ct * 32 + l31;   // same col for all 32 scores
        #pragma unroll
        for (int rt = 0; rt < 2; ++rt) {
            f32x16 ch; f32x16 cl;
            #pragma unroll
            for (int e = 0; e < 16; ++e) { ch[e] = 0.f; cl[e] = 0.f; }
            ch = __builtin_amdgcn_mfma_f32_32x32x16_f16(afr[rt][0], cb[0], ch, 0, 0, 0);
            ch = __builtin_amdgcn_mfma_f32_32x32x16_f16(afr[rt][1], cb[1], ch, 0, 0, 0);
            ch = __builtin_amdgcn_mfma_f32_32x32x16_f16(afr[rt][2], cb[2], ch, 0, 0, 0);
            cl = __builtin_amdgcn_mfma_f32_32x32x16_f16(afr[rt][0], cb[3], cl, 0, 0, 0);
            cl = __builtin_amdgcn_mfma_f32_32x32x16_f16(afr[rt][1], cb[4], cl, 0, 0, 0);
            cl = __builtin_amdgcn_mfma_f32_32x32x16_f16(afr[rt][2], cb[5], cl, 0, 0, 0);
            #pragma unroll
            for (int e = 0; e < 16; ++e) {
                const float s = fmaf(cl[e], INV_LO, ch[e]);
                if (s > best[rt][e]) bidx[rt][e] = mycol;   // cols ascend: > keeps first
                best[rt][e] = fmaxf(best[rt][e], s);
            }
        }
        #pragma unroll
        for (int q = 0; q < 6; ++q) cb[q] = nb[q];
    }

    // Cross-lane argmax over the 32 cols held by l31=0..31 (same half).
    // Tie -> smaller index (jnp.argmax first-index semantics).
    #pragma unroll
    for (int m = 1; m < 32; m <<= 1) {
        #pragma unroll
        for (int rt = 0; rt < 2; ++rt)
            #pragma unroll
            for (int e = 0; e < 16; ++e) {
                const float ov = __shfl_xor(best[rt][e], m, 64);
                const int   oi = __shfl_xor(bidx[rt][e], m, 64);
                if (ov > best[rt][e] ||
                    (ov == best[rt][e] && oi < bidx[rt][e])) {
                    best[rt][e] = ov; bidx[rt][e] = oi;
                }
            }
    }

    if (l31 == 0) {   // lanes 0 and 32 write their half's rows
        #pragma unroll
        for (int rt = 0; rt < 2; ++rt)
            #pragma unroll
            for (int e = 0; e < 16; ++e) {
                const int row = rowbase + rt * 32 + (e & 3) + 8 * (e >> 2) + 4 * half;
                pbest[(size_t)row * NCHUNK + chunk] = best[rt][e];
                pidx [(size_t)row * NCHUNK + chunk] = bidx[rt][e];
            }
    }
}

// ---------------------------------------------------------------------------
// Fold the 4 chunk partials (ascending chunk + strict > == global first-index
// argmax), gather LUT, write out (1024,8,10,2).
__global__ void reduce_lut_kernel(const float* __restrict__ pbest,
                                  const int*   __restrict__ pidx,
                                  const float* __restrict__ LUT,  // (10,4096,2)
                                  float* __restrict__ out) {
    const int row = blockIdx.x * blockDim.x + threadIdx.x;
    if (row >= M_ROWS) return;
    float best = -INFINITY;
    int   bi   = 0;
    #pragma unroll
    for (int ch = 0; ch < NCHUNK; ++ch) {
        const float bv = pbest[(size_t)row * NCHUNK + ch];
        const int   ix = pidx [(size_t)row * NCHUNK + ch];
        if (bv > best) { best = bv; bi = ix; }
    }
    const int pair = row / 10;
    const int c2   = row - pair * 10;
    const float* l = LUT + ((size_t)c2 * NCOLS + bi) * 2;
    out[row * 2 + 0] = l[0];
    out[row * 2 + 1] = l[1];
}

// ---------------------------------------------------------------------------
extern "C" void kernel_launch(void* const* d_in, const int* in_sizes, int n_in,
                              void* d_out, int out_size, void* d_ws, size_t ws_size,
                              hipStream_t stream) {
    const float* x   = (const float*)d_in[0];  // 1024*480
    const float* S   = (const float*)d_in[1];  // 30*2*15
    const float* T   = (const float*)d_in[2];  // 30*15
    const float* H   = (const float*)d_in[3];  // 45*4096
    const float* LUT = (const float*)d_in[4];  // 10*4096*2
    float* out = (float*)d_out;                // 1024*8*10*2

    _Float16* Bhi_pk = (_Float16*)d_ws;                         // 128*1536
    _Float16* Blo_pk = Bhi_pk + (size_t)GROUNDS * ROUNDH;       // 128*1536
    float*  pbest = (float*)(Blo_pk + (size_t)GROUNDS * ROUNDH);
    int*    pidx  = (int*)(pbest + (size_t)M_ROWS * NCHUNK);

    build_B_kernel<<<16, 256, 0, stream>>>(H, Bhi_pk, Blo_pk);
    // 5120 waves = 1280 row-groups x 4 chunks; 4 waves/block, chunk-uniform blocks
    score_argmax_kernel<<<1280, 256, 0, stream>>>(x, S, T, Bhi_pk, Blo_pk, pbest, pidx);
    reduce_lut_kernel<<<M_ROWS / 256, 256, 0, stream>>>(pbest, pidx, LUT, out);
}

// Round 7
// 194.334 us; speedup vs baseline: 1.9028x; 1.9028x over previous
//
#include <hip/hip_runtime.h>
#include <math.h>

// Problem constants (N = 1024)
#define M_ROWS  81920            // 1024*8*10 score rows
#define NCOLS   4096
#define KPAD    48               // 45 padded to 48 (3 k-tiles of 16 for 32x32x16)
#define NCHUNK  4
#define CHUNKC  (NCOLS / NCHUNK) // 1024 cols per chunk
#define CROUNDS (CHUNKC / 32)    // 32 col-rounds of 32 cols per chunk
#define GROUNDS (NCOLS / 32)     // 128 global rounds
#define FRAG    512              // halves per fragment block (64 lanes x 8)
#define ROUNDH  (3 * FRAG)       // halves per round per matrix (3 k-tiles)
#define LO_SCALE 4096.0f         // 2^12: keeps f16 residuals out of subnormal range
#define INV_LO   (1.0f / 4096.0f)

typedef _Float16 f16x8  __attribute__((ext_vector_type(8)));
typedef float    f32x16 __attribute__((ext_vector_type(16)));

// ws layout (~3.4 MB). ORDER MATTERS: the pipelined GEMM's final prefetch
// overreads one round (3 KB) past Bhi_pk (lands in Blo_pk) and past Blo_pk
// (lands in pbest) — values unused, memory must be valid.
//   Bhi_pk: _Float16[128 * 1536]  (MFMA-fragment order)   384 KB
//   Blo_pk: _Float16[128 * 1536]  (residual * 2^12)       384 KB
//   pbest : float[81920 * 4]                              1.31 MB
//   pidx  : int  [81920 * 4]                              1.31 MB

// ---------------------------------------------------------------------------
// Build B in MFMA-fragment order. For round r (cols 32r..32r+31), k-tile kt,
// the 1 KB block at (r*3+kt)*FRAG holds lane l's 8 halves at l*8:
//   lane l = half*32 + l31  ->  B[k = kt*16 + half*8 + j][col = 32r + l31].
__global__ void build_B_kernel(const float* __restrict__ H,
                               _Float16* __restrict__ Bhi_pk,
                               _Float16* __restrict__ Blo_pk) {
    const int n = blockIdx.x * 256 + threadIdx.x;
    const int r = n >> 5;
    const int l = n & 31;
    float hi[KPAD], lo[KPAD];
    #pragma unroll
    for (int k = 0; k < 45; ++k) {
        const float h = H[k * NCOLS + n];
        const _Float16 h1 = (_Float16)h;
        hi[k] = (float)h1;
        lo[k] = (h - (float)h1) * LO_SCALE;
    }
    #pragma unroll
    for (int k = 45; k < KPAD; ++k) { hi[k] = 0.f; lo[k] = 0.f; }
    #pragma unroll
    for (int kt = 0; kt < 3; ++kt) {
        f16x8 h0, h1v, l0, l1v;
        #pragma unroll
        for (int j = 0; j < 8; ++j) {
            h0[j]  = (_Float16)hi[kt * 16 + j];
            h1v[j] = (_Float16)hi[kt * 16 + 8 + j];
            l0[j]  = (_Float16)lo[kt * 16 + j];
            l1v[j] = (_Float16)lo[kt * 16 + 8 + j];
        }
        _Float16* dh = Bhi_pk + (size_t)(r * 3 + kt) * FRAG;
        _Float16* dl = Blo_pk + (size_t)(r * 3 + kt) * FRAG;
        *(f16x8*)(dh + l * 8)        = h0;    // half 0 lane
        *(f16x8*)(dh + (l + 32) * 8) = h1v;   // half 1 lane
        *(f16x8*)(dl + l * 8)        = l0;
        *(f16x8*)(dl + (l + 32) * 8) = l1v;
    }
}

// ---------------------------------------------------------------------------
// MFMA GEMM + fused argmax, 32x32x16 shape, inline A, packed coalesced B.
// wave = 64 rows (2 row-tiles of 32) x 1024-col chunk, 32-col rounds,
// branch-free double-buffered B prefetch (loads are base + lane*16 + imm:
// one 1 KB fully-coalesced transaction each).
// NOTE: __launch_bounds__ kept at (256,2). (256,4) in R5 capped VGPRs at 64
// and spilled accumulators to scratch: WRITE_SIZE 2.6MB -> 847MB, 2.3x slower.
// 32x32 layouts (m74/m101-verified): A[m=lane&31][k=(lane>>5)*8+j];
// B[k=(lane>>5)*8+j][n=lane&31]; C/D col=lane&31, row=(e&3)+8*(e>>2)+4*(lane>>5).
__global__ __launch_bounds__(256, 2) void score_argmax_kernel(
        const float* __restrict__ x,   // (1024, 480)
        const float* __restrict__ S,   // (30, 2, 15)
        const float* __restrict__ T,   // (30, 15)
        const _Float16* __restrict__ Bhi_pk,
        const _Float16* __restrict__ Blo_pk,
        float* __restrict__ pbest,
        int*   __restrict__ pidx) {
    const int tid  = threadIdx.x;
    const int lane = tid & 63;
    const int l31  = lane & 31;
    const int half = lane >> 5;                       // 0 or 1
    const int chunk = blockIdx.x / 320;               // block-uniform
    const int rg    = (blockIdx.x - chunk * 320) * 4 + (tid >> 6);  // [0,1280)
    const int rowbase = rg * 64;

    // ---- inline A: afr[rt][kt][j] = y(rowbase + rt*32 + l31, kt*16 + half*8 + j)
    // y = sign(x4·S - T - 1e-4), exactly ±1/0 in f16; zero for k >= 45.
    f16x8 afr[2][3];
    #pragma unroll
    for (int rt = 0; rt < 2; ++rt) {
        const int row  = rowbase + rt * 32 + l31;
        const int pair = row / 10;
        const int c2   = row - pair * 10;
        const int a    = pair >> 3;
        const int b    = pair & 7;
        const float* xp = x + a * 480 + b * 60;
        #pragma unroll
        for (int kt = 0; kt < 3; ++kt) {
            #pragma unroll
            for (int j = 0; j < 8; ++j) {
                const int k    = kt * 16 + half * 8 + j;     // [0,48)
                const bool pad = (k >= 45);
                const int kcl  = pad ? 0 : k;                // clamp for safe addrs
                const int cc   = kcl / 15;
                const int kk   = kcl - cc * 15;
                const int c    = c2 * 3 + cc;
                const float x0 = xp[c * 2 + 0];
                const float x1 = xp[c * 2 + 1];
                float v = x0 * S[(c * 2 + 0) * 15 + kk] + x1 * S[(c * 2 + 1) * 15 + kk];
                v = v - T[c * 15 + kk] - 1e-4f;
                const float yv = (v > 0.f) ? 1.f : ((v < 0.f) ? -1.f : 0.f);
                afr[rt][kt][j] = pad ? (_Float16)0.f : (_Float16)yv;
            }
        }
    }

    float best[2][16];
    int   bidx[2][16];
    #pragma unroll
    for (int rt = 0; rt < 2; ++rt)
        #pragma unroll
        for (int e = 0; e < 16; ++e) { best[rt][e] = -INFINITY; bidx[rt][e] = 0; }

    const int colbase0 = chunk * CHUNKC;
    // per-lane packed base for this chunk's first round
    const _Float16* hbase = Bhi_pk + (size_t)(chunk * CROUNDS) * ROUNDH + lane * 8;
    const _Float16* lbase = Blo_pk + (size_t)(chunk * CROUNDS) * ROUNDH + lane * 8;

    // double-buffered B fragments (hi/lo x 3 k-tiles); all loads unconditional.
    f16x8 cb[6], nb[6];
    #pragma unroll
    for (int kt = 0; kt < 3; ++kt) {
        cb[kt]     = *(const f16x8*)(hbase + kt * FRAG);
        cb[3 + kt] = *(const f16x8*)(lbase + kt * FRAG);
    }

    for (int ct = 0; ct < CROUNDS; ++ct) {
        // prefetch round ct+1 (final iter overreads 3KB into adjacent ws: valid)
        {
            const _Float16* hp = hbase + (size_t)(ct + 1) * ROUNDH;
            const _Float16* lp = lbase + (size_t)(ct + 1) * ROUNDH;
            #pragma unroll
            for (int kt = 0; kt < 3; ++kt) {
                nb[kt]     = *(const f16x8*)(hp + kt * FRAG);
                nb[3 + kt] = *(const f16x8*)(lp + kt * FRAG);
            }
        }
        const int mycol = colbase0 + ct * 32 + l31;   // same col for all 32 scores
        #pragma unroll
        for (int rt = 0; rt < 2; ++rt) {
            f32x16 ch; f32x16 cl;
            #pragma unroll
            for (int e = 0; e < 16; ++e) { ch[e] = 0.f; cl[e] = 0.f; }
            ch = __builtin_amdgcn_mfma_f32_32x32x16_f16(afr[rt][0], cb[0], ch, 0, 0, 0);
            ch = __builtin_amdgcn_mfma_f32_32x32x16_f16(afr[rt][1], cb[1], ch, 0, 0, 0);
            ch = __builtin_amdgcn_mfma_f32_32x32x16_f16(afr[rt][2], cb[2], ch, 0, 0, 0);
            cl = __builtin_amdgcn_mfma_f32_32x32x16_f16(afr[rt][0], cb[3], cl, 0, 0, 0);
            cl = __builtin_amdgcn_mfma_f32_32x32x16_f16(afr[rt][1], cb[4], cl, 0, 0, 0);
            cl = __builtin_amdgcn_mfma_f32_32x32x16_f16(afr[rt][2], cb[5], cl, 0, 0, 0);
            #pragma unroll
            for (int e = 0; e < 16; ++e) {
                const float s = fmaf(cl[e], INV_LO, ch[e]);
                if (s > best[rt][e]) bidx[rt][e] = mycol;   // cols ascend: > keeps first
                best[rt][e] = fmaxf(best[rt][e], s);
            }
        }
        #pragma unroll
        for (int q = 0; q < 6; ++q) cb[q] = nb[q];
    }

    // Cross-lane argmax over the 32 cols held by l31=0..31 (same half).
    // Tie -> smaller index (jnp.argmax first-index semantics).
    #pragma unroll
    for (int m = 1; m < 32; m <<= 1) {
        #pragma unroll
        for (int rt = 0; rt < 2; ++rt)
            #pragma unroll
            for (int e = 0; e < 16; ++e) {
                const float ov = __shfl_xor(best[rt][e], m, 64);
                const int   oi = __shfl_xor(bidx[rt][e], m, 64);
                if (ov > best[rt][e] ||
                    (ov == best[rt][e] && oi < bidx[rt][e])) {
                    best[rt][e] = ov; bidx[rt][e] = oi;
                }
            }
    }

    if (l31 == 0) {   // lanes 0 and 32 write their half's rows
        #pragma unroll
        for (int rt = 0; rt < 2; ++rt)
            #pragma unroll
            for (int e = 0; e < 16; ++e) {
                const int row = rowbase + rt * 32 + (e & 3) + 8 * (e >> 2) + 4 * half;
                pbest[(size_t)row * NCHUNK + chunk] = best[rt][e];
                pidx [(size_t)row * NCHUNK + chunk] = bidx[rt][e];
            }
    }
}

// ---------------------------------------------------------------------------
// Fold the 4 chunk partials (ascending chunk + strict > == global first-index
// argmax), gather LUT, write out (1024,8,10,2).
__global__ void reduce_lut_kernel(const float* __restrict__ pbest,
                                  const int*   __restrict__ pidx,
                                  const float* __restrict__ LUT,  // (10,4096,2)
                                  float* __restrict__ out) {
    const int row = blockIdx.x * blockDim.x + threadIdx.x;
    if (row >= M_ROWS) return;
    float best = -INFINITY;
    int   bi   = 0;
    #pragma unroll
    for (int ch = 0; ch < NCHUNK; ++ch) {
        const float bv = pbest[(size_t)row * NCHUNK + ch];
        const int   ix = pidx [(size_t)row * NCHUNK + ch];
        if (bv > best) { best = bv; bi = ix; }
    }
    const int pair = row / 10;
    const int c2   = row - pair * 10;
    const float* l = LUT + ((size_t)c2 * NCOLS + bi) * 2;
    out[row * 2 + 0] = l[0];
    out[row * 2 + 1] = l[1];
}

// ---------------------------------------------------------------------------
extern "C" void kernel_launch(void* const* d_in, const int* in_sizes, int n_in,
                              void* d_out, int out_size, void* d_ws, size_t ws_size,
                              hipStream_t stream) {
    const float* x   = (const float*)d_in[0];  // 1024*480
    const float* S   = (const float*)d_in[1];  // 30*2*15
    const float* T   = (const float*)d_in[2];  // 30*15
    const float* H   = (const float*)d_in[3];  // 45*4096
    const float* LUT = (const float*)d_in[4];  // 10*4096*2
    float* out = (float*)d_out;                // 1024*8*10*2

    _Float16* Bhi_pk = (_Float16*)d_ws;                         // 128*1536
    _Float16* Blo_pk = Bhi_pk + (size_t)GROUNDS * ROUNDH;       // 128*1536
    float*  pbest = (float*)(Blo_pk + (size_t)GROUNDS * ROUNDH);
    int*    pidx  = (int*)(pbest + (size_t)M_ROWS * NCHUNK);

    build_B_kernel<<<16, 256, 0, stream>>>(H, Bhi_pk, Blo_pk);
    // 5120 waves = 1280 row-groups x 4 chunks; 4 waves/block, chunk-uniform blocks
    score_argmax_kernel<<<1280, 256, 0, stream>>>(x, S, T, Bhi_pk, Blo_pk, pbest, pidx);
    reduce_lut_kernel<<<M_ROWS / 256, 256, 0, stream>>>(pbest, pidx, LUT, out);
}